// Round 1
// baseline (2668.880 us; speedup 1.0000x reference)
//
#include <hip/hip_runtime.h>
#include <math.h>

#define BN 4096
#define FD 512
#define TILE 128
#define NJB (BN / TILE)   // 32 j-tiles
#define KC 32
#define SK 36             // LDS row stride (32 + 4 pad, 144 B: 16B-aligned)

__device__ __forceinline__ float wred_sum(float v) {
#pragma unroll
  for (int m = 1; m < 64; m <<= 1) v += __shfl_xor(v, m, 64);
  return v;
}

__device__ __forceinline__ float dot4(float4 a, float4 b) {
  return a.x * b.x + a.y * b.y + a.z * b.z + a.w * b.w;
}

// ---------------- Kernel 1: normalize rows + recon partial ----------------
__global__ __launch_bounds__(64) void k_prep(const float* __restrict__ f,
                                             const float* __restrict__ fo,
                                             float* __restrict__ g,
                                             float* __restrict__ acc) {
  const int i = blockIdx.x;
  const int lane = threadIdx.x;
  const float4* fr = (const float4*)(f + (size_t)i * FD);
  const float4* orr = (const float4*)(fo + (size_t)i * FD);
  float4 x0 = fr[lane], x1 = fr[lane + 64];
  float4 y0 = orr[lane], y1 = orr[lane + 64];
  float sff = dot4(x0, x0) + dot4(x1, x1);
  float sfo = dot4(x0, y0) + dot4(x1, y1);
  float soo = dot4(y0, y0) + dot4(y1, y1);
  sff = wred_sum(sff);
  sfo = wred_sum(sfo);
  soo = wred_sum(soo);
  float nf = sqrtf(sff);
  float inv = 1.0f / nf;
  float4* gr = (float4*)(g + (size_t)i * FD);
  gr[lane] = make_float4(x0.x * inv, x0.y * inv, x0.z * inv, x0.w * inv);
  gr[lane + 64] = make_float4(x1.x * inv, x1.y * inv, x1.z * inv, x1.w * inv);
  if (lane == 0) {
    float c = sfo / fmaxf(nf * sqrtf(soo), 1e-8f);
    atomicAdd(&acc[2], c);
  }
}

// ---- Kernel 2: tiled g·gT with masked per-row argmax epilogue ----
// grid (NJB, NJB), 256 threads. Tile 128x128, per-thread 8x8, KC=32.
__global__ __launch_bounds__(256) void k_sim(const float* __restrict__ g,
                                             const int* __restrict__ labels,
                                             const float* __restrict__ angles,
                                             float* __restrict__ pval,
                                             int* __restrict__ pidx) {
  __shared__ float As[TILE * SK];
  __shared__ float Bs[TILE * SK];
  const int tid = threadIdx.x;
  const int tx = tid & 15;
  const int ty = tid >> 4;
  const int i0 = blockIdx.y * TILE;
  const int j0 = blockIdx.x * TILE;

  float acc[8][8];
#pragma unroll
  for (int u = 0; u < 8; u++)
#pragma unroll
    for (int v = 0; v < 8; v++) acc[u][v] = 0.0f;

  const int lrow = tid >> 1;          // 0..127
  const int lq = (tid & 1) * 4;       // first quad of this thread

  for (int kc = 0; kc < FD; kc += KC) {
#pragma unroll
    for (int s = 0; s < 4; s++) {
      int q = lq + s;                 // 0..7 (quad within 32-float chunk)
      float4 va = *(const float4*)(g + (size_t)(i0 + lrow) * FD + kc + q * 4);
      *(float4*)(&As[lrow * SK + q * 4]) = va;
      float4 vb = *(const float4*)(g + (size_t)(j0 + lrow) * FD + kc + q * 4);
      *(float4*)(&Bs[lrow * SK + q * 4]) = vb;
    }
    __syncthreads();
#pragma unroll
    for (int k4 = 0; k4 < KC; k4 += 4) {
      float4 a[8], b[8];
#pragma unroll
      for (int u = 0; u < 8; u++)
        a[u] = *(const float4*)(&As[(ty + 16 * u) * SK + k4]);
#pragma unroll
      for (int v = 0; v < 8; v++)
        b[v] = *(const float4*)(&Bs[(tx + 16 * v) * SK + k4]);
#pragma unroll
      for (int u = 0; u < 8; u++)
#pragma unroll
        for (int v = 0; v < 8; v++) acc[u][v] += dot4(a[u], b[v]);
    }
    __syncthreads();
  }

  // Epilogue: mask = (labels differ) && (angle dist < 30); per-row argmax.
  int li[8], lj[8];
  float ai[8][3], aj[8][3];
#pragma unroll
  for (int u = 0; u < 8; u++) {
    int i = i0 + ty + 16 * u;
    li[u] = labels[i];
    ai[u][0] = angles[i * 3 + 0];
    ai[u][1] = angles[i * 3 + 1];
    ai[u][2] = angles[i * 3 + 2];
  }
#pragma unroll
  for (int v = 0; v < 8; v++) {
    int j = j0 + tx + 16 * v;
    lj[v] = labels[j];
    aj[v][0] = angles[j * 3 + 0];
    aj[v][1] = angles[j * 3 + 1];
    aj[v][2] = angles[j * 3 + 2];
  }

#pragma unroll
  for (int u = 0; u < 8; u++) {
    float best = -1e30f;
    int bidx = 2147483647;
#pragma unroll
    for (int v = 0; v < 8; v++) {
      int j = j0 + tx + 16 * v;
      float d0 = ai[u][0] - aj[v][0];
      float d1 = ai[u][1] - aj[v][1];
      float d2 = ai[u][2] - aj[v][2];
      float dd = d0 * d0 + d1 * d1 + d2 * d2;
      bool m = (li[u] != lj[v]) && (sqrtf(dd) < 30.0f);
      if (m && acc[u][v] > best) {  // ascending j within thread -> first max
        best = acc[u][v];
        bidx = j;
      }
    }
    // reduce across the 16 tx lanes sharing this row
#pragma unroll
    for (int off = 1; off < 16; off <<= 1) {
      float ov = __shfl_xor(best, off, 16);
      int oi = __shfl_xor(bidx, off, 16);
      if (ov > best || (ov == best && oi < bidx)) {
        best = ov;
        bidx = oi;
      }
    }
    if (tx == 0) {
      int i = i0 + ty + 16 * u;
      pval[(size_t)i * NJB + blockIdx.x] = best;
      pidx[(size_t)i * NJB + blockIdx.x] = bidx;
    }
  }
}

// ---------------- Kernel 3: per-row finalize (one wave per row) ----------------
__global__ __launch_bounds__(64) void k_final(const float* __restrict__ f,
                                              const int* __restrict__ labels,
                                              const float* __restrict__ angles,
                                              const float* __restrict__ pval,
                                              const int* __restrict__ pidx,
                                              float* __restrict__ acc) {
  const int i = blockIdx.x;
  const int lane = threadIdx.x;
  const int li = labels[i];
  const float a0 = angles[i * 3 + 0];
  const float a1 = angles[i * 3 + 1];
  const float a2 = angles[i * 3 + 2];

  // scan all j: hardest positive (max adist, same label, j!=i),
  // fallback negative (min adist, diff label)
  float bpv = -1.0f;
  int bp = 0;
  float bnv = 1e30f;
  int bn = 0;
  bool hp = false, hn = false;
  for (int j = lane; j < BN; j += 64) {
    int lj = labels[j];
    float d0 = a0 - angles[j * 3 + 0];
    float d1 = a1 - angles[j * 3 + 1];
    float d2 = a2 - angles[j * 3 + 2];
    float dd = d0 * d0 + d1 * d1 + d2 * d2;
    if (lj == li) {
      if (j != i) {
        hp = true;
        if (dd > bpv) { bpv = dd; bp = j; }
      }
    } else {
      hn = true;
      if (dd < bnv) { bnv = dd; bn = j; }
    }
  }
#pragma unroll
  for (int off = 1; off < 64; off <<= 1) {
    float ov = __shfl_xor(bpv, off, 64);
    int oi = __shfl_xor(bp, off, 64);
    if (ov > bpv || (ov == bpv && oi < bp)) { bpv = ov; bp = oi; }
    ov = __shfl_xor(bnv, off, 64);
    oi = __shfl_xor(bn, off, 64);
    if (ov < bnv || (ov == bnv && oi < bn)) { bnv = ov; bn = oi; }
  }
  hp = __any(hp);
  hn = __any(hn);

  // combine sim-argmax partials (32 j-tiles)
  float sv = (lane < NJB) ? pval[(size_t)i * NJB + lane] : -1e30f;
  int si = (lane < NJB) ? pidx[(size_t)i * NJB + lane] : 2147483647;
#pragma unroll
  for (int off = 1; off < 64; off <<= 1) {
    float ov = __shfl_xor(sv, off, 64);
    int oi = __shfl_xor(si, off, 64);
    if (ov > sv || (ov == sv && oi < si)) { sv = ov; si = oi; }
  }
  bool sim_any = sv > -5e29f;
  int neg = sim_any ? si : bn;
  int pos = bp;

  // triplet distances (reference adds 1e-6 to the per-element difference)
  const float* fa = f + (size_t)i * FD;
  const float* fp = f + (size_t)pos * FD;
  const float* fn = f + (size_t)neg * FD;
  float sp = 0.0f, sn = 0.0f;
  for (int t = lane; t < FD; t += 64) {
    float dp = fa[t] - fp[t] + 1e-6f;
    sp += dp * dp;
    float dn = fa[t] - fn[t] + 1e-6f;
    sn += dn * dn;
  }
  sp = wred_sum(sp);
  sn = wred_sum(sn);

  if (lane == 0 && hp && hn) {
    float pos_d = sqrtf(sp);
    float neg_d = sqrtf(sn);
    float p0 = a0 - angles[pos * 3 + 0];
    float p1 = a1 - angles[pos * 3 + 1];
    float p2 = a2 - angles[pos * 3 + 2];
    float pa = sqrtf(p0 * p0 + p1 * p1 + p2 * p2);
    float n0 = a0 - angles[neg * 3 + 0];
    float n1 = a1 - angles[neg * 3 + 1];
    float n2 = a2 - angles[neg * 3 + 2];
    float na = sqrtf(n0 * n0 + n1 * n1 + n2 * n2);
    float w = (pa > 45.0f ? 2.0f : 1.0f) * (na < 15.0f ? 1.5f : 1.0f);
    float basic = fmaxf(pos_d - neg_d + 0.2f, 0.0f);
    atomicAdd(&acc[0], w * basic);
    atomicAdd(&acc[1], 1.0f);
  }
}

// ---------------- Kernel 4: scalar assembly ----------------
__global__ void k_out(const float* __restrict__ acc, float* __restrict__ out) {
  float cnt = fmaxf(acc[1], 1.0f);
  float tri = acc[0] / cnt;
  float recon = 1.0f - acc[2] / (float)BN;
  out[0] = tri + 0.1f * recon;
}

extern "C" void kernel_launch(void* const* d_in, const int* in_sizes, int n_in,
                              void* d_out, int out_size, void* d_ws, size_t ws_size,
                              hipStream_t stream) {
  const float* feat = (const float*)d_in[0];
  const int* labels = (const int*)d_in[1];
  const float* angles = (const float*)d_in[2];
  const float* forig = (const float*)d_in[3];
  float* out = (float*)d_out;

  char* ws = (char*)d_ws;
  float* g = (float*)ws;                                       // 8 MB normalized rows
  size_t off = (size_t)BN * FD * sizeof(float);
  float* pval = (float*)(ws + off);                            // 512 KB
  off += (size_t)BN * NJB * sizeof(float);
  int* pidx = (int*)(ws + off);                                // 512 KB
  off += (size_t)BN * NJB * sizeof(int);
  float* acc = (float*)(ws + off);                             // 3 accumulators

  hipMemsetAsync(acc, 0, 4 * sizeof(float), stream);
  k_prep<<<BN, 64, 0, stream>>>(feat, forig, g, acc);
  dim3 gs(NJB, NJB);
  k_sim<<<gs, 256, 0, stream>>>(g, labels, angles, pval, pidx);
  k_final<<<BN, 64, 0, stream>>>(feat, labels, angles, pval, pidx, acc);
  k_out<<<1, 1, 0, stream>>>(acc, out);
}

// Round 2
// 293.553 us; speedup vs baseline: 9.0917x; 9.0917x over previous
//
#include <hip/hip_runtime.h>
#include <math.h>

#define BN 4096
#define FD 512
#define TILE 128
#define BK 32
#define NJB 32            // 128-wide j tiles
#define NPC 64            // partials per row: 32 tiles x 2 wave-stripes

typedef __attribute__((ext_vector_type(8))) __bf16 bf16x8;
typedef __attribute__((ext_vector_type(4))) float floatx4;

__device__ __forceinline__ float wred_sum(float v) {
#pragma unroll
  for (int m = 1; m < 64; m <<= 1) v += __shfl_xor(v, m, 64);
  return v;
}

__device__ __forceinline__ float dot4(float4 a, float4 b) {
  return a.x * b.x + a.y * b.y + a.z * b.z + a.w * b.w;
}

// round-to-nearest-even f32 -> bf16 (values are finite, |x| ~ 0.05)
__device__ __forceinline__ unsigned short f2bf(float x) {
  unsigned u = __float_as_uint(x);
  u += 0x7fffu + ((u >> 16) & 1u);
  return (unsigned short)(u >> 16);
}

__device__ __forceinline__ void load16(const void* g, void* l) {
  __builtin_amdgcn_global_load_lds(
      (const __attribute__((address_space(1))) unsigned int*)g,
      (__attribute__((address_space(3))) unsigned int*)l, 16, 0, 0);
}

// ------- Kernel 1: normalize rows -> bf16 g, recon partial -------
__global__ __launch_bounds__(64) void k_prep(const float* __restrict__ f,
                                             const float* __restrict__ fo,
                                             unsigned short* __restrict__ gb,
                                             float* __restrict__ acc) {
  const int i = blockIdx.x;
  const int lane = threadIdx.x;
  const float4* fr = (const float4*)(f + (size_t)i * FD);
  const float4* orr = (const float4*)(fo + (size_t)i * FD);
  float4 x0 = fr[lane], x1 = fr[lane + 64];
  float4 y0 = orr[lane], y1 = orr[lane + 64];
  float sff = dot4(x0, x0) + dot4(x1, x1);
  float sfo = dot4(x0, y0) + dot4(x1, y1);
  float soo = dot4(y0, y0) + dot4(y1, y1);
  sff = wred_sum(sff);
  sfo = wred_sum(sfo);
  soo = wred_sum(soo);
  float nf = sqrtf(sff);
  float inv = 1.0f / nf;
  ushort4* gr = (ushort4*)(gb + (size_t)i * FD);
  ushort4 s0, s1;
  s0.x = f2bf(x0.x * inv); s0.y = f2bf(x0.y * inv);
  s0.z = f2bf(x0.z * inv); s0.w = f2bf(x0.w * inv);
  s1.x = f2bf(x1.x * inv); s1.y = f2bf(x1.y * inv);
  s1.z = f2bf(x1.z * inv); s1.w = f2bf(x1.w * inv);
  gr[lane] = s0;
  gr[lane + 64] = s1;
  if (lane == 0) {
    float c = sfo / fmaxf(nf * sqrtf(soo), 1e-8f);
    atomicAdd(&acc[2], c);
  }
}

// ------- Kernel 2: bf16 MFMA g.gT with fused masked-argmax epilogue -------
// grid (NJB, NJB) x 256 threads (4 waves, 2x2). Tile 128x128, BK=32.
__global__ __launch_bounds__(256) void k_sim(const unsigned short* __restrict__ gb,
                                             const int* __restrict__ labels,
                                             const float* __restrict__ angles,
                                             float* __restrict__ pval,
                                             int* __restrict__ pidx) {
  __shared__ unsigned short As[TILE * BK];   // row-major, 64B rows
  __shared__ unsigned short Bs[TILE * BK];
  const int tid = threadIdx.x;
  const int w = tid >> 6;
  const int lane = tid & 63;
  const int wi = w >> 1, wj = w & 1;
  const int i0 = blockIdx.y * TILE;
  const int j0 = blockIdx.x * TILE;

  floatx4 acc[4][4];
#pragma unroll
  for (int u = 0; u < 4; u++)
#pragma unroll
    for (int v = 0; v < 4; v++) acc[u][v] = (floatx4){0.f, 0.f, 0.f, 0.f};

  // staging: chunk c (16B) -> LDS offset c*16; c = row*4 + col16
  const int r1 = tid >> 2;          // rows 0..63
  const int q8 = (tid & 3) * 8;     // ushort offset of 16B chunk in row
  const unsigned short* gA1 = gb + (size_t)(i0 + r1) * FD + q8;
  const unsigned short* gA2 = gA1 + (size_t)64 * FD;
  const unsigned short* gB1 = gb + (size_t)(j0 + r1) * FD + q8;
  const unsigned short* gB2 = gB1 + (size_t)64 * FD;
  unsigned short* lA1 = As + tid * 8;
  unsigned short* lA2 = As + (tid + 256) * 8;
  unsigned short* lB1 = Bs + tid * 8;
  unsigned short* lB2 = Bs + (tid + 256) * 8;

  const int arow = wi * 64 + (lane & 15);   // + u*16
  const int brow = wj * 64 + (lane & 15);   // + v*16
  const int koff = (lane >> 4) * 8;         // k element offset in frag

  for (int kc = 0; kc < FD; kc += BK) {
    load16(gA1 + kc, lA1);
    load16(gA2 + kc, lA2);
    load16(gB1 + kc, lB1);
    load16(gB2 + kc, lB2);
    __syncthreads();
    bf16x8 a[4], b[4];
#pragma unroll
    for (int u = 0; u < 4; u++)
      a[u] = *(const bf16x8*)(As + (arow + u * 16) * BK + koff);
#pragma unroll
    for (int v = 0; v < 4; v++)
      b[v] = *(const bf16x8*)(Bs + (brow + v * 16) * BK + koff);
#pragma unroll
    for (int u = 0; u < 4; u++)
#pragma unroll
      for (int v = 0; v < 4; v++)
        acc[u][v] = __builtin_amdgcn_mfma_f32_16x16x32_bf16(a[u], b[v], acc[u][v], 0, 0, 0);
    __syncthreads();
  }

  // Epilogue: C layout col=lane&15, row=quad*4+reg (16x16 family).
  const int quad = lane >> 4;
  const int cx = lane & 15;
  int jc[4], lj[4];
  float aj[4][3];
#pragma unroll
  for (int v = 0; v < 4; v++) {
    jc[v] = j0 + wj * 64 + v * 16 + cx;
    lj[v] = labels[jc[v]];
    aj[v][0] = angles[jc[v] * 3 + 0];
    aj[v][1] = angles[jc[v] * 3 + 1];
    aj[v][2] = angles[jc[v] * 3 + 2];
  }
#pragma unroll
  for (int u = 0; u < 4; u++) {
#pragma unroll
    for (int reg = 0; reg < 4; reg++) {
      int i = i0 + wi * 64 + u * 16 + quad * 4 + reg;
      int li = labels[i];
      float a0 = angles[i * 3 + 0];
      float a1 = angles[i * 3 + 1];
      float a2 = angles[i * 3 + 2];
      float best = -1e30f;
      int bidx = 0x7fffffff;
#pragma unroll
      for (int v = 0; v < 4; v++) {
        float d0 = a0 - aj[v][0];
        float d1 = a1 - aj[v][1];
        float d2 = a2 - aj[v][2];
        float dd = d0 * d0 + d1 * d1 + d2 * d2;
        float val = acc[u][v][reg];
        if ((li != lj[v]) && (dd < 900.0f) && val > best) {  // sqrt(dd)<30
          best = val;
          bidx = jc[v];
        }
      }
#pragma unroll
      for (int off = 1; off < 16; off <<= 1) {
        float ov = __shfl_xor(best, off, 16);
        int oi = __shfl_xor(bidx, off, 16);
        if (ov > best || (ov == best && oi < bidx)) { best = ov; bidx = oi; }
      }
      if (cx == 0) {
        pval[(size_t)i * NPC + blockIdx.x * 2 + wj] = best;
        pidx[(size_t)i * NPC + blockIdx.x * 2 + wj] = bidx;
      }
    }
  }
}

// ------- Kernel 3: per-row finalize (one wave per row) -------
__global__ __launch_bounds__(64) void k_final(const float* __restrict__ f,
                                              const int* __restrict__ labels,
                                              const float* __restrict__ angles,
                                              const float* __restrict__ pval,
                                              const int* __restrict__ pidx,
                                              float* __restrict__ acc) {
  const int i = blockIdx.x;
  const int lane = threadIdx.x;
  const int li = labels[i];
  const float a0 = angles[i * 3 + 0];
  const float a1 = angles[i * 3 + 1];
  const float a2 = angles[i * 3 + 2];

  float bpv = -1.0f;
  int bp = 0;
  float bnv = 1e30f;
  int bn = 0;
  bool hp = false, hn = false;
  for (int j = lane; j < BN; j += 64) {
    int lj = labels[j];
    float d0 = a0 - angles[j * 3 + 0];
    float d1 = a1 - angles[j * 3 + 1];
    float d2 = a2 - angles[j * 3 + 2];
    float dd = d0 * d0 + d1 * d1 + d2 * d2;
    if (lj == li) {
      if (j != i) {
        hp = true;
        if (dd > bpv) { bpv = dd; bp = j; }
      }
    } else {
      hn = true;
      if (dd < bnv) { bnv = dd; bn = j; }
    }
  }
#pragma unroll
  for (int off = 1; off < 64; off <<= 1) {
    float ov = __shfl_xor(bpv, off, 64);
    int oi = __shfl_xor(bp, off, 64);
    if (ov > bpv || (ov == bpv && oi < bp)) { bpv = ov; bp = oi; }
    ov = __shfl_xor(bnv, off, 64);
    oi = __shfl_xor(bn, off, 64);
    if (ov < bnv || (ov == bnv && oi < bn)) { bnv = ov; bn = oi; }
  }
  hp = __any(hp);
  hn = __any(hn);

  // combine 64 sim-argmax partials
  float sv = pval[(size_t)i * NPC + lane];
  int si = pidx[(size_t)i * NPC + lane];
#pragma unroll
  for (int off = 1; off < 64; off <<= 1) {
    float ov = __shfl_xor(sv, off, 64);
    int oi = __shfl_xor(si, off, 64);
    if (ov > sv || (ov == sv && oi < si)) { sv = ov; si = oi; }
  }
  bool sim_any = sv > -5e29f;
  int neg = sim_any ? si : bn;
  int pos = bp;

  const float* fa = f + (size_t)i * FD;
  const float* fp = f + (size_t)pos * FD;
  const float* fn = f + (size_t)neg * FD;
  float sp = 0.0f, sn = 0.0f;
  for (int t = lane; t < FD; t += 64) {
    float dp = fa[t] - fp[t] + 1e-6f;
    sp += dp * dp;
    float dn = fa[t] - fn[t] + 1e-6f;
    sn += dn * dn;
  }
  sp = wred_sum(sp);
  sn = wred_sum(sn);

  if (lane == 0 && hp && hn) {
    float pos_d = sqrtf(sp);
    float neg_d = sqrtf(sn);
    float p0 = a0 - angles[pos * 3 + 0];
    float p1 = a1 - angles[pos * 3 + 1];
    float p2 = a2 - angles[pos * 3 + 2];
    float pa = sqrtf(p0 * p0 + p1 * p1 + p2 * p2);
    float n0 = a0 - angles[neg * 3 + 0];
    float n1 = a1 - angles[neg * 3 + 1];
    float n2 = a2 - angles[neg * 3 + 2];
    float na = sqrtf(n0 * n0 + n1 * n1 + n2 * n2);
    float w = (pa > 45.0f ? 2.0f : 1.0f) * (na < 15.0f ? 1.5f : 1.0f);
    float basic = fmaxf(pos_d - neg_d + 0.2f, 0.0f);
    atomicAdd(&acc[0], w * basic);
    atomicAdd(&acc[1], 1.0f);
  }
}

// ------- Kernel 4: scalar assembly -------
__global__ void k_out(const float* __restrict__ acc, float* __restrict__ out) {
  float cnt = fmaxf(acc[1], 1.0f);
  float tri = acc[0] / cnt;
  float recon = 1.0f - acc[2] / (float)BN;
  out[0] = tri + 0.1f * recon;
}

extern "C" void kernel_launch(void* const* d_in, const int* in_sizes, int n_in,
                              void* d_out, int out_size, void* d_ws, size_t ws_size,
                              hipStream_t stream) {
  const float* feat = (const float*)d_in[0];
  const int* labels = (const int*)d_in[1];
  const float* angles = (const float*)d_in[2];
  const float* forig = (const float*)d_in[3];
  float* out = (float*)d_out;

  char* ws = (char*)d_ws;
  unsigned short* gb = (unsigned short*)ws;                    // 4 MB bf16 normalized rows
  size_t off = (size_t)BN * FD * sizeof(unsigned short);
  float* pval = (float*)(ws + off);                            // 1 MB
  off += (size_t)BN * NPC * sizeof(float);
  int* pidx = (int*)(ws + off);                                // 1 MB
  off += (size_t)BN * NPC * sizeof(int);
  float* acc = (float*)(ws + off);                             // accumulators

  hipMemsetAsync(acc, 0, 4 * sizeof(float), stream);
  k_prep<<<BN, 64, 0, stream>>>(feat, forig, gb, acc);
  dim3 gs(NJB, NJB);
  k_sim<<<gs, 256, 0, stream>>>(gb, labels, angles, pval, pidx);
  k_final<<<BN, 64, 0, stream>>>(feat, labels, angles, pval, pidx, acc);
  k_out<<<1, 1, 0, stream>>>(acc, out);
}